// Round 8
// baseline (135.655 us; speedup 1.0000x reference)
//
#include <hip/hip_runtime.h>
#include <stdint.h>

typedef __attribute__((ext_vector_type(8))) short short8;
typedef __attribute__((ext_vector_type(4))) float f32x4;

#define BB 8
#define CC 256
#define PP 1024
#define NH 4
#define DH 64

__device__ __forceinline__ unsigned short f2bf(float f) {
  union { float f; unsigned u; } v; v.f = f;
  unsigned r = v.u + 0x7FFFu + ((v.u >> 16) & 1u);
  return (unsigned short)(r >> 16);
}

__device__ __forceinline__ float bf2f(unsigned short u) {
  union { unsigned u; float f; } v; v.u = ((unsigned)u) << 16;
  return v.f;
}

__device__ __forceinline__ f32x4 mfma16(short8 a, short8 b, f32x4 c) {
  return __builtin_amdgcn_mfma_f32_16x16x32_bf16(a, b, c, 0, 0, 0);
}

// -------- Kernel 1: GroupNorm partial sums (512 blk) + weight cvt (256 blk) -
__global__ __launch_bounds__(256) void prep(
    const float* __restrict__ x, float2* __restrict__ part,
    const float* __restrict__ qkvw, const float* __restrict__ projw,
    unsigned short* __restrict__ wall) {
  int blk = blockIdx.x;
  int tid = threadIdx.x;
  if (blk < 512) {
    int sl = blk & 7, g = (blk >> 3) & 7, b = blk >> 6;
    const float4* xb =
        (const float4*)(x + (size_t)(b * CC + g * 32) * PP) + sl * 1024;
    float s = 0.f, q = 0.f;
    for (int i = tid; i < 1024; i += 256) {
      float4 v = xb[i];
      s += v.x + v.y + v.z + v.w;
      q += v.x * v.x + v.y * v.y + v.z * v.z + v.w * v.w;
    }
    for (int off = 32; off > 0; off >>= 1) {
      s += __shfl_down(s, off);
      q += __shfl_down(q, off);
    }
    __shared__ float rs[4], rq[4];
    int w = tid >> 6;
    if ((tid & 63) == 0) { rs[w] = s; rq[w] = q; }
    __syncthreads();
    if (tid == 0)
      part[blk] = make_float2(rs[0] + rs[1] + rs[2] + rs[3],
                              rq[0] + rq[1] + rq[2] + rq[3]);
  } else {
    int i4 = (blk - 512) * 256 + tid;  // 65536 float4s total
    float4 v = (i4 < 49152) ? ((const float4*)qkvw)[i4]
                            : ((const float4*)projw)[i4 - 49152];
    ushort4 o;
    o.x = f2bf(v.x); o.y = f2bf(v.y); o.z = f2bf(v.z); o.w = f2bf(v.w);
    ((ushort4*)wall)[i4] = o;
  }
}

// ------------- Kernel 2: finish stats + normalize + transpose --------------
// -> xnT[b][p][c] bf16
__global__ __launch_bounds__(256) void norm_t(
    const float* __restrict__ x, const float2* __restrict__ part,
    const float* __restrict__ gamma, const float* __restrict__ beta,
    unsigned short* __restrict__ xnT) {
  int p0 = blockIdx.x * 64, c0 = blockIdx.y * 64, b = blockIdx.z;
  int tid = threadIdx.x;
  __shared__ float ms[2], rstd[2];
  __shared__ unsigned short T[64][72];
  if (tid < 2) {
    int g = blockIdx.y * 2 + tid;
    float S = 0.f, Q = 0.f;
    for (int i = 0; i < 8; ++i) {
      float2 pp = part[b * 64 + g * 8 + i];
      S += pp.x; Q += pp.y;
    }
    float mean = S * (1.f / 32768.f);
    float var = Q * (1.f / 32768.f) - mean * mean;
    ms[tid] = mean;
    rstd[tid] = rsqrtf(var + 1e-5f);
  }
  __syncthreads();
  for (int it = 0; it < 4; ++it) {
    int l = tid + 256 * it;
    int cc = l >> 4, p4 = l & 15;
    int c = c0 + cc, gi = cc >> 5;
    float sc = rstd[gi] * gamma[c];
    float sh = beta[c] - ms[gi] * sc;
    float4 v = *(const float4*)(x + (size_t)(b * CC + c) * PP + p0 + p4 * 4);
    T[p4 * 4 + 0][cc] = f2bf(v.x * sc + sh);
    T[p4 * 4 + 1][cc] = f2bf(v.y * sc + sh);
    T[p4 * 4 + 2][cc] = f2bf(v.z * sc + sh);
    T[p4 * 4 + 3][cc] = f2bf(v.w * sc + sh);
  }
  __syncthreads();
  for (int it = 0; it < 2; ++it) {
    int l = tid + 256 * it;
    int p = l >> 3, seg = l & 7;
    *(short8*)(xnT + ((size_t)b * PP + p0 + p) * CC + c0 + seg * 8) =
        *(const short8*)&T[p][seg * 8];
  }
}

// ------------- Kernel 3: QKV GEMM (computed [p][o]) ------------------------
// q,k: [b][h][p][64]; v stored TRANSPOSED: vT[b][h][ch][p]
__global__ __launch_bounds__(256) void qkv_gemm(
    const unsigned short* __restrict__ xnT, const unsigned short* __restrict__ wbf,
    const float* __restrict__ qkvb, unsigned short* __restrict__ qb,
    unsigned short* __restrict__ kb, unsigned short* __restrict__ vT) {
  int p0 = blockIdx.x * 128, o0 = blockIdx.y * 128, b = blockIdx.z;
  int tid = threadIdx.x;
  int w = tid >> 6, lane = tid & 63, lq = lane >> 4, ln = lane & 15;
  int wy = w >> 1, wx = w & 1;
  __shared__ unsigned short A_l[128][40];
  __shared__ unsigned short B_l[128][40];
  f32x4 acc[4][4];
  for (int i = 0; i < 4; ++i)
    for (int j = 0; j < 4; ++j) acc[i][j] = (f32x4){0.f, 0.f, 0.f, 0.f};
  for (int kc = 0; kc < 256; kc += 32) {
    for (int it = 0; it < 2; ++it) {
      int l = tid + 256 * it;
      int row = l >> 2, seg = l & 3;
      *(short8*)&A_l[row][seg * 8] =
          *(const short8*)(xnT + ((size_t)b * PP + p0 + row) * CC + kc + seg * 8);
      *(short8*)&B_l[row][seg * 8] =
          *(const short8*)(wbf + (size_t)(o0 + row) * CC + kc + seg * 8);
    }
    __syncthreads();
    short8 af[4], bf[4];
    for (int i = 0; i < 4; ++i)
      af[i] = *(const short8*)&A_l[wy * 64 + i * 16 + ln][lq * 8];
    for (int j = 0; j < 4; ++j)
      bf[j] = *(const short8*)&B_l[wx * 64 + j * 16 + ln][lq * 8];
    for (int i = 0; i < 4; ++i)
      for (int j = 0; j < 4; ++j) acc[i][j] = mfma16(af[i], bf[j], acc[i][j]);
    __syncthreads();
  }
  for (int i = 0; i < 4; ++i) {
    for (int j = 0; j < 4; ++j) {
      int o = o0 + wx * 64 + j * 16 + ln;
      int s = o >> 8, h = (o >> 6) & 3, ch = o & 63;
      float bias = qkvb[o];
      float mul = (s == 0) ? 0.125f : 1.0f;  // fold dh^-0.5 into q
      size_t bh = (size_t)b * NH + h;
      for (int r = 0; r < 4; ++r) {
        int p = p0 + wy * 64 + i * 16 + lq * 4 + r;
        unsigned short val = f2bf((acc[i][j][r] + bias) * mul);
        if (s == 2) {
          vT[(bh * DH + ch) * PP + p] = val;
        } else {
          unsigned short* dst = (s == 0) ? qb : kb;
          dst[(bh * PP + p) * DH + ch] = val;
        }
      }
    }
  }
}

// ------------- Kernel 4: flash attention, BARRIER-FREE main loop -----------
// K ([e][ch]) and vT ([ch][e]) global layouts ARE the MFMA A-frag layouts,
// so each wave loads K/V fragments directly from global (L2-resident) and
// needs LDS only for its PRIVATE P round-trip (C->B layout). Wave w sweeps
// e in [w*256, w*256+256) in 32-e chunks; no __syncthreads until the final
// cross-wave partial-O reduction. d-tile 32 -> grid 1024 (4 blocks/CU),
// LDS 18.9 KB, launch_bounds(256,4) -> 16 waves/CU of free-running TLP.
// No-max softmax safe: s = 0.125*q.k ~ N(0,1); clamp 60 blocks overflow.
__global__ __launch_bounds__(256, 4) void attn(
    const unsigned short* __restrict__ qb, const unsigned short* __restrict__ kb,
    const unsigned short* __restrict__ vT, unsigned short* __restrict__ attnT) {
  int d0 = blockIdx.x * 32, h = blockIdx.y, b = blockIdx.z;
  int tid = threadIdx.x;
  int w = tid >> 6, lane = tid & 63, lq = lane >> 4, ln = lane & 15;
  size_t bh = (size_t)b * NH + h;
  const unsigned short* qbase = qb + bh * PP * DH;
  const unsigned short* kbase = kb + bh * PP * DH;
  const unsigned short* vbase = vT + bh * DH * PP;

  __shared__ __align__(16) char SM[18944];
  unsigned short* P_l = (unsigned short*)(SM + w * 2560);  // private [32][40]
  unsigned short* Obf = (unsigned short*)SM;               // [4][32][72] alias
  float* lsums = (float*)(SM + 18432);                     // [4][32]

  // Q frags: qf[ds][kc] = Q[d0+ds*16+ln][kc*32+lq*8 ..+7]
  short8 qf[2][2];
#pragma unroll
  for (int ds = 0; ds < 2; ++ds)
#pragma unroll
    for (int kc = 0; kc < 2; ++kc)
      qf[ds][kc] = *(const short8*)(qbase + (size_t)(d0 + ds * 16 + ln) * DH +
                                    kc * 32 + lq * 8);

  float lsum[2] = {0.f, 0.f};
  f32x4 o_acc[4][2];
#pragma unroll
  for (int i = 0; i < 4; ++i)
#pragma unroll
    for (int j = 0; j < 2; ++j) o_acc[i][j] = (f32x4){0.f, 0.f, 0.f, 0.f};

  for (int sub = 0; sub < 8; ++sub) {
    int e0 = w * 256 + sub * 32;
    // K frags direct from global: 16 e-rows x 64 ch contiguous per (es,kc)
    short8 kf[2][2], vf[4];
#pragma unroll
    for (int es = 0; es < 2; ++es)
#pragma unroll
      for (int kc = 0; kc < 2; ++kc)
        kf[es][kc] = *(const short8*)(kbase + (size_t)(e0 + es * 16 + ln) * DH +
                                      kc * 32 + lq * 8);
    // V frags direct from global: rows ch, k-major in e
#pragma unroll
    for (int cs = 0; cs < 4; ++cs)
      vf[cs] = *(const short8*)(vbase + (size_t)(cs * 16 + ln) * PP + e0 + lq * 8);
    // QK: S^T; C col = d = ds*16+ln, row = e_local = es*16+lq*4+r
    f32x4 sc[2][2];
#pragma unroll
    for (int es = 0; es < 2; ++es)
#pragma unroll
      for (int ds = 0; ds < 2; ++ds) {
        f32x4 a = (f32x4){0.f, 0.f, 0.f, 0.f};
        a = mfma16(kf[es][0], qf[ds][0], a);
        a = mfma16(kf[es][1], qf[ds][1], a);
        sc[es][ds] = a;
      }
    // exp + pack -> private P (b64 writes), accumulate row-sums
#pragma unroll
    for (int es = 0; es < 2; ++es)
#pragma unroll
      for (int ds = 0; ds < 2; ++ds) {
        float p0 = __expf(fminf(sc[es][ds][0], 60.f));
        float p1 = __expf(fminf(sc[es][ds][1], 60.f));
        float p2 = __expf(fminf(sc[es][ds][2], 60.f));
        float p3 = __expf(fminf(sc[es][ds][3], 60.f));
        lsum[ds] += (p0 + p1) + (p2 + p3);
        union { unsigned short u[4]; unsigned long long ll; } pk;
        pk.u[0] = f2bf(p0); pk.u[1] = f2bf(p1);
        pk.u[2] = f2bf(p2); pk.u[3] = f2bf(p3);
        *(unsigned long long*)&P_l[(ds * 16 + ln) * 40 + es * 16 + lq * 4] =
            pk.ll;
      }
    // PV: O[ch][d] += V[ch][e] * P[d][e] over this 32-e chunk
    short8 pb[2];
#pragma unroll
    for (int ds = 0; ds < 2; ++ds)
      pb[ds] = *(const short8*)&P_l[(ds * 16 + ln) * 40 + lq * 8];
#pragma unroll
    for (int cs = 0; cs < 4; ++cs)
#pragma unroll
      for (int ds = 0; ds < 2; ++ds)
        o_acc[cs][ds] = mfma16(vf[cs], pb[ds], o_acc[cs][ds]);
  }
  __syncthreads();  // all waves done with private P; safe to alias Obf
  // partial row-sums: col d = ds*16+ln, reduce over quads
#pragma unroll
  for (int ds = 0; ds < 2; ++ds) {
    float s = lsum[ds];
    s += __shfl_xor(s, 16);
    s += __shfl_xor(s, 32);
    if (lq == 0) lsums[w * 32 + ds * 16 + ln] = s;
  }
  // bf16 partial O -> Obf[w][d][ch]
#pragma unroll
  for (int cs = 0; cs < 4; ++cs)
#pragma unroll
    for (int ds = 0; ds < 2; ++ds) {
      union { unsigned short u[4]; unsigned long long ll; } pk;
#pragma unroll
      for (int r = 0; r < 4; ++r) pk.u[r] = f2bf(o_acc[cs][ds][r]);
      *(unsigned long long*)&Obf[(w * 32 + ds * 16 + ln) * 72 + cs * 16 +
                                 lq * 4] = pk.ll;
    }
  __syncthreads();
  // final: sum 4 partials, normalize, store direct to global
  {
    int d = tid >> 3, cseg = tid & 7;
    float inv =
        1.f / (lsums[d] + lsums[32 + d] + lsums[64 + d] + lsums[96 + d]);
    float o[8];
#pragma unroll
    for (int j = 0; j < 8; ++j) o[j] = 0.f;
#pragma unroll
    for (int ww = 0; ww < 4; ++ww) {
      short8 vv = *(const short8*)&Obf[(ww * 32 + d) * 72 + cseg * 8];
#pragma unroll
      for (int r = 0; r < 8; ++r) o[r] += bf2f((unsigned short)vv[r]);
    }
    union { unsigned short u[8]; short8 s; } pk;
#pragma unroll
    for (int j = 0; j < 8; ++j) pk.u[j] = f2bf(o[j] * inv);
    *(short8*)(attnT + ((size_t)b * PP + d0 + d) * CC + h * DH + cseg * 8) =
        pk.s;
  }
}

// ------------- Kernel 5: proj GEMM + bias + residual (fp32 out) ------------
__global__ __launch_bounds__(256) void proj_gemm(
    const unsigned short* __restrict__ attnT, const unsigned short* __restrict__ pwbf,
    const float* __restrict__ projb, const float* __restrict__ x,
    float* __restrict__ out) {
  int p0 = blockIdx.x * 128, o0 = blockIdx.y * 64, b = blockIdx.z;
  int tid = threadIdx.x;
  int w = tid >> 6, lane = tid & 63, lq = lane >> 4, ln = lane & 15;
  __shared__ unsigned short A_l[64][40];
  __shared__ unsigned short B_l[128][40];
  f32x4 acc[4][2];
  for (int i = 0; i < 4; ++i)
    for (int j = 0; j < 2; ++j) acc[i][j] = (f32x4){0.f, 0.f, 0.f, 0.f};
  for (int kc = 0; kc < 256; kc += 32) {
    {
      int row = tid >> 2, seg = tid & 3;
      *(short8*)&A_l[row][seg * 8] =
          *(const short8*)(pwbf + (size_t)(o0 + row) * CC + kc + seg * 8);
    }
    for (int it = 0; it < 2; ++it) {
      int l = tid + 256 * it;
      int row = l >> 2, seg = l & 3;
      *(short8*)&B_l[row][seg * 8] =
          *(const short8*)(attnT + ((size_t)b * PP + p0 + row) * CC + kc + seg * 8);
    }
    __syncthreads();
    short8 af[4], bfr[2];
    for (int i = 0; i < 4; ++i)
      af[i] = *(const short8*)&A_l[i * 16 + ln][lq * 8];
    for (int j = 0; j < 2; ++j)
      bfr[j] = *(const short8*)&B_l[w * 32 + j * 16 + ln][lq * 8];
    for (int i = 0; i < 4; ++i)
      for (int j = 0; j < 2; ++j) acc[i][j] = mfma16(af[i], bfr[j], acc[i][j]);
    __syncthreads();
  }
  for (int i = 0; i < 4; ++i) {
    for (int j = 0; j < 2; ++j) {
      int p = p0 + w * 32 + j * 16 + ln;
      for (int r = 0; r < 4; ++r) {
        int o = o0 + i * 16 + lq * 4 + r;
        size_t idx = ((size_t)b * CC + o) * PP + p;
        out[idx] = x[idx] + projb[o] + acc[i][j][r];
      }
    }
  }
}

// ---------------------------------------------------------------------------
extern "C" void kernel_launch(void* const* d_in, const int* in_sizes, int n_in,
                              void* d_out, int out_size, void* d_ws, size_t ws_size,
                              hipStream_t stream) {
  const float* x = (const float*)d_in[0];
  const float* gamma = (const float*)d_in[1];
  const float* beta = (const float*)d_in[2];
  const float* qkvw = (const float*)d_in[3];
  const float* qkvb = (const float*)d_in[4];
  const float* projw = (const float*)d_in[5];
  const float* projb = (const float*)d_in[6];
  float* out = (float*)d_out;
  char* ws = (char*)d_ws;

  float2* part = (float2*)(ws + 0);                        //  4 KB
  unsigned short* xnT = (unsigned short*)(ws + 16384);     //  4 MB
  unsigned short* wall = (unsigned short*)(ws + 4210688);  // 512 KB
  unsigned short* pwbf = wall + 768 * 256;
  unsigned short* qb = (unsigned short*)(ws + 4734976);      // 4 MB
  unsigned short* kb = (unsigned short*)(ws + 8929280);      // 4 MB
  unsigned short* vT = (unsigned short*)(ws + 13123584);     // 4 MB
  unsigned short* attnT = (unsigned short*)(ws + 17317888);  // 4 MB

  prep<<<768, 256, 0, stream>>>(x, part, qkvw, projw, wall);
  norm_t<<<dim3(16, 4, 8), 256, 0, stream>>>(x, part, gamma, beta, xnT);
  qkv_gemm<<<dim3(8, 6, 8), 256, 0, stream>>>(xnT, wall, qkvb, qb, kb, vT);
  attn<<<dim3(32, 4, 8), 256, 0, stream>>>(qb, kb, vT, attnT);
  proj_gemm<<<dim3(8, 4, 8), 256, 0, stream>>>(attnT, pwbf, projb, x, out);
}

// Round 9
// 126.823 us; speedup vs baseline: 1.0696x; 1.0696x over previous
//
#include <hip/hip_runtime.h>
#include <stdint.h>

typedef __attribute__((ext_vector_type(8))) short short8;
typedef __attribute__((ext_vector_type(4))) float f32x4;

#define BB 8
#define CC 256
#define PP 1024
#define NH 4
#define DH 64

__device__ __forceinline__ unsigned short f2bf(float f) {
  union { float f; unsigned u; } v; v.f = f;
  unsigned r = v.u + 0x7FFFu + ((v.u >> 16) & 1u);
  return (unsigned short)(r >> 16);
}

__device__ __forceinline__ f32x4 mfma16(short8 a, short8 b, f32x4 c) {
  return __builtin_amdgcn_mfma_f32_16x16x32_bf16(a, b, c, 0, 0, 0);
}

typedef __attribute__((address_space(3))) unsigned int lds_u32;
typedef const __attribute__((address_space(1))) unsigned int glob_u32;

// async global->LDS DMA, 16 B per lane; LDS dest = base + lane*16
__device__ __forceinline__ void gl_lds16(const unsigned short* g,
                                         unsigned short* l) {
  __builtin_amdgcn_global_load_lds((glob_u32*)g, (lds_u32*)l, 16, 0, 0);
}

// -------- Kernel 1: GroupNorm partial sums (512 blk) + weight cvt (256 blk) -
__global__ __launch_bounds__(256) void prep(
    const float* __restrict__ x, float2* __restrict__ part,
    const float* __restrict__ qkvw, const float* __restrict__ projw,
    unsigned short* __restrict__ wall) {
  int blk = blockIdx.x;
  int tid = threadIdx.x;
  if (blk < 512) {
    int sl = blk & 7, g = (blk >> 3) & 7, b = blk >> 6;
    const float4* xb =
        (const float4*)(x + (size_t)(b * CC + g * 32) * PP) + sl * 1024;
    float s = 0.f, q = 0.f;
    for (int i = tid; i < 1024; i += 256) {
      float4 v = xb[i];
      s += v.x + v.y + v.z + v.w;
      q += v.x * v.x + v.y * v.y + v.z * v.z + v.w * v.w;
    }
    for (int off = 32; off > 0; off >>= 1) {
      s += __shfl_down(s, off);
      q += __shfl_down(q, off);
    }
    __shared__ float rs[4], rq[4];
    int w = tid >> 6;
    if ((tid & 63) == 0) { rs[w] = s; rq[w] = q; }
    __syncthreads();
    if (tid == 0)
      part[blk] = make_float2(rs[0] + rs[1] + rs[2] + rs[3],
                              rq[0] + rq[1] + rq[2] + rq[3]);
  } else {
    int i4 = (blk - 512) * 256 + tid;  // 65536 float4s total
    float4 v = (i4 < 49152) ? ((const float4*)qkvw)[i4]
                            : ((const float4*)projw)[i4 - 49152];
    ushort4 o;
    o.x = f2bf(v.x); o.y = f2bf(v.y); o.z = f2bf(v.z); o.w = f2bf(v.w);
    ((ushort4*)wall)[i4] = o;
  }
}

// ------------- Kernel 2: finish stats + normalize + transpose --------------
// -> xnT[b][p][c] bf16
__global__ __launch_bounds__(256) void norm_t(
    const float* __restrict__ x, const float2* __restrict__ part,
    const float* __restrict__ gamma, const float* __restrict__ beta,
    unsigned short* __restrict__ xnT) {
  int p0 = blockIdx.x * 64, c0 = blockIdx.y * 64, b = blockIdx.z;
  int tid = threadIdx.x;
  __shared__ float ms[2], rstd[2];
  __shared__ unsigned short T[64][72];
  if (tid < 2) {
    int g = blockIdx.y * 2 + tid;
    float S = 0.f, Q = 0.f;
    for (int i = 0; i < 8; ++i) {
      float2 pp = part[b * 64 + g * 8 + i];
      S += pp.x; Q += pp.y;
    }
    float mean = S * (1.f / 32768.f);
    float var = Q * (1.f / 32768.f) - mean * mean;
    ms[tid] = mean;
    rstd[tid] = rsqrtf(var + 1e-5f);
  }
  __syncthreads();
  for (int it = 0; it < 4; ++it) {
    int l = tid + 256 * it;
    int cc = l >> 4, p4 = l & 15;
    int c = c0 + cc, gi = cc >> 5;
    float sc = rstd[gi] * gamma[c];
    float sh = beta[c] - ms[gi] * sc;
    float4 v = *(const float4*)(x + (size_t)(b * CC + c) * PP + p0 + p4 * 4);
    T[p4 * 4 + 0][cc] = f2bf(v.x * sc + sh);
    T[p4 * 4 + 1][cc] = f2bf(v.y * sc + sh);
    T[p4 * 4 + 2][cc] = f2bf(v.z * sc + sh);
    T[p4 * 4 + 3][cc] = f2bf(v.w * sc + sh);
  }
  __syncthreads();
  for (int it = 0; it < 2; ++it) {
    int l = tid + 256 * it;
    int p = l >> 3, seg = l & 7;
    *(short8*)(xnT + ((size_t)b * PP + p0 + p) * CC + c0 + seg * 8) =
        *(const short8*)&T[p][seg * 8];
  }
}

// ------------- Kernel 3: QKV GEMM (computed [p][o]), gl_lds staging --------
// q,k: [b][h][p][64]; v stored TRANSPOSED: vT[b][h][ch][p]
__global__ __launch_bounds__(256) void qkv_gemm(
    const unsigned short* __restrict__ xnT, const unsigned short* __restrict__ wbf,
    const float* __restrict__ qkvb, unsigned short* __restrict__ qb,
    unsigned short* __restrict__ kb, unsigned short* __restrict__ vT) {
  int p0 = blockIdx.x * 128, o0 = blockIdx.y * 128, b = blockIdx.z;
  int tid = threadIdx.x;
  int w = tid >> 6, lane = tid & 63, lq = lane >> 4, ln = lane & 15;
  int wy = w >> 1, wx = w & 1;
  __shared__ unsigned short A_l[128 * 32];
  __shared__ unsigned short B_l[128 * 32];
  f32x4 acc[4][4];
  for (int i = 0; i < 4; ++i)
    for (int j = 0; j < 4; ++j) acc[i][j] = (f32x4){0.f, 0.f, 0.f, 0.f};
  int rrow = lane >> 2, rseg = lane & 3;  // lane -> (row-in-16, 8-short seg)
  for (int kc = 0; kc < 256; kc += 32) {
#pragma unroll
    for (int i = 0; i < 2; ++i) {
      int row = i * 64 + w * 16 + rrow;
      gl_lds16(xnT + ((size_t)b * PP + p0 + row) * CC + kc + rseg * 8,
               &A_l[(i * 64 + w * 16) * 32]);
      gl_lds16(wbf + (size_t)(o0 + row) * CC + kc + rseg * 8,
               &B_l[(i * 64 + w * 16) * 32]);
    }
    __syncthreads();
    short8 af[4], bf[4];
    for (int i = 0; i < 4; ++i)
      af[i] = *(const short8*)&A_l[(wy * 64 + i * 16 + ln) * 32 + lq * 8];
    for (int j = 0; j < 4; ++j)
      bf[j] = *(const short8*)&B_l[(wx * 64 + j * 16 + ln) * 32 + lq * 8];
    for (int i = 0; i < 4; ++i)
      for (int j = 0; j < 4; ++j) acc[i][j] = mfma16(af[i], bf[j], acc[i][j]);
    __syncthreads();
  }
  for (int i = 0; i < 4; ++i) {
    for (int j = 0; j < 4; ++j) {
      int o = o0 + wx * 64 + j * 16 + ln;
      int s = o >> 8, h = (o >> 6) & 3, ch = o & 63;
      float bias = qkvb[o];
      float mul = (s == 0) ? 0.125f : 1.0f;  // fold dh^-0.5 into q
      size_t bh = (size_t)b * NH + h;
      for (int r = 0; r < 4; ++r) {
        int p = p0 + wy * 64 + i * 16 + lq * 4 + r;
        unsigned short val = f2bf((acc[i][j][r] + bias) * mul);
        if (s == 2) {
          vT[(bh * DH + ch) * PP + p] = val;
        } else {
          unsigned short* dst = (s == 0) ? qb : kb;
          dst[(bh * PP + p) * DH + ch] = val;
        }
      }
    }
  }
}

// ------------- Kernel 4: flash attention, S^T form (R6 best) ---------------
// QK computed as S^T = K Q^T (swap mfma operands): C/D col = d, rows = e.
// P-regs contiguous in e => 8x ds_write_b64; row-sum is per-lane scalar,
// reduced once at end via shfl_xor(16/32). PV as O = V^T(.)P.
// No-max softmax safe: s = 0.125*q.k ~ N(0,1); clamp 60 blocks overflow.
__global__ __launch_bounds__(256) void attn(
    const unsigned short* __restrict__ qb, const unsigned short* __restrict__ kb,
    const unsigned short* __restrict__ vT, unsigned short* __restrict__ attnT) {
  int d0 = blockIdx.x * 64, h = blockIdx.y, b = blockIdx.z;
  int tid = threadIdx.x;
  int w = tid >> 6, lane = tid & 63, lq = lane >> 4, ln = lane & 15;
  size_t bh = (size_t)b * NH + h;
  const unsigned short* qbase = qb + bh * PP * DH;
  const unsigned short* kbase = kb + bh * PP * DH;
  const unsigned short* vbase = vT + bh * DH * PP;
  __shared__ unsigned short K_l[128][72];   // [e][ch]
  __shared__ unsigned short V_l[64][136];   // [ch][e]
  __shared__ unsigned short P_l[64][140];   // [d][e], b64-aligned rows
  unsigned short (*O_l)[72] = (unsigned short (*)[72]) & P_l[0][0];

  int ke = tid >> 1, kseg = tid & 1;   // K: 128 rows x 2 half-rows x 32 shorts
  int vch = tid >> 2, vseg = tid & 3;  // V: 64 rows x 4 quarter-rows x 32 shorts

  short8 qf[2];
  {
    int d = d0 + w * 16 + ln;
    qf[0] = *(const short8*)(qbase + (size_t)d * DH + lq * 8);
    qf[1] = *(const short8*)(qbase + (size_t)d * DH + 32 + lq * 8);
  }
  float l_sum = 0.f;  // partial row-sum for d = w*16+ln (this lane's column)
  f32x4 o_acc[4];
  for (int i = 0; i < 4; ++i) o_acc[i] = (f32x4){0.f, 0.f, 0.f, 0.f};

  short8 kr[4], vr[4];
#pragma unroll
  for (int i = 0; i < 4; ++i)
    kr[i] = *(const short8*)(kbase + (size_t)ke * DH + kseg * 32 + i * 8);
#pragma unroll
  for (int i = 0; i < 4; ++i)
    vr[i] = *(const short8*)(vbase + (size_t)vch * PP + vseg * 32 + i * 8);

  for (int e0 = 0; e0 < PP; e0 += 128) {
#pragma unroll
    for (int i = 0; i < 4; ++i)
      *(short8*)&K_l[ke][kseg * 32 + i * 8] = kr[i];
#pragma unroll
    for (int i = 0; i < 4; ++i)
      *(short8*)&V_l[vch][vseg * 32 + i * 8] = vr[i];
    if (e0 + 128 < PP) {
      int en = e0 + 128;
#pragma unroll
      for (int i = 0; i < 4; ++i)
        kr[i] = *(const short8*)(kbase + (size_t)(en + ke) * DH + kseg * 32 + i * 8);
#pragma unroll
      for (int i = 0; i < 4; ++i)
        vr[i] = *(const short8*)(vbase + (size_t)vch * PP + en + vseg * 32 + i * 8);
    }
    __syncthreads();
    // S^T = K Q^T : 8 subtiles of 16 e. A = K_l rows e, B = Q rows d.
    f32x4 sc[8];
#pragma unroll
    for (int ns = 0; ns < 8; ++ns) {
      f32x4 a = (f32x4){0.f, 0.f, 0.f, 0.f};
      a = mfma16(*(const short8*)&K_l[ns * 16 + ln][lq * 8], qf[0], a);
      a = mfma16(*(const short8*)&K_l[ns * 16 + ln][32 + lq * 8], qf[1], a);
      sc[ns] = a;
    }
    // exp + pack 4 contiguous-e values -> one b64 LDS write per subtile
#pragma unroll
    for (int ns = 0; ns < 8; ++ns) {
      float p0 = __expf(fminf(sc[ns][0], 60.f));
      float p1 = __expf(fminf(sc[ns][1], 60.f));
      float p2 = __expf(fminf(sc[ns][2], 60.f));
      float p3 = __expf(fminf(sc[ns][3], 60.f));
      l_sum += (p0 + p1) + (p2 + p3);
      union { unsigned short u[4]; unsigned long long ll; } pk;
      pk.u[0] = f2bf(p0); pk.u[1] = f2bf(p1);
      pk.u[2] = f2bf(p2); pk.u[3] = f2bf(p3);
      *(unsigned long long*)&P_l[w * 16 + ln][ns * 16 + lq * 4] = pk.ll;
    }
    // PV: C[ch][d] += sum_e V_l[ch][e] * P_l[d][e]; 4 k-chunks of 32 e
#pragma unroll
    for (int t = 0; t < 4; ++t) {
      short8 pb = *(const short8*)&P_l[w * 16 + ln][t * 32 + lq * 8];
#pragma unroll
      for (int cs = 0; cs < 4; ++cs)
        o_acc[cs] = mfma16(
            *(const short8*)&V_l[cs * 16 + ln][t * 32 + lq * 8], pb, o_acc[cs]);
    }
    __syncthreads();
  }
  // cross-quad row-sum reduce (d = w*16+ln lives in lane ln of every quad)
  float rsum = l_sum;
  rsum += __shfl_xor(rsum, 16);
  rsum += __shfl_xor(rsum, 32);
  float inv = 1.f / rsum;
  // O frag: lane holds col d = w*16+ln, rows ch = cs*16+lq*4+r -> b64 packs
#pragma unroll
  for (int cs = 0; cs < 4; ++cs) {
    union { unsigned short u[4]; unsigned long long ll; } pk;
#pragma unroll
    for (int r = 0; r < 4; ++r) pk.u[r] = f2bf(o_acc[cs][r] * inv);
    *(unsigned long long*)&O_l[w * 16 + ln][cs * 16 + lq * 4] = pk.ll;
  }
  __syncthreads();
  for (int it = 0; it < 2; ++it) {
    int l = tid + 256 * it;
    int dd = l >> 3, seg = l & 7;
    *(short8*)(attnT + ((size_t)b * PP + d0 + dd) * CC + h * DH + seg * 8) =
        *(const short8*)&O_l[dd][seg * 8];
  }
}

// ------------- Kernel 5: proj GEMM + bias + residual, gl_lds staging -------
__global__ __launch_bounds__(256) void proj_gemm(
    const unsigned short* __restrict__ attnT, const unsigned short* __restrict__ pwbf,
    const float* __restrict__ projb, const float* __restrict__ x,
    float* __restrict__ out) {
  int p0 = blockIdx.x * 128, o0 = blockIdx.y * 64, b = blockIdx.z;
  int tid = threadIdx.x;
  int w = tid >> 6, lane = tid & 63, lq = lane >> 4, ln = lane & 15;
  __shared__ unsigned short A_l[64 * 32];
  __shared__ unsigned short B_l[128 * 32];
  f32x4 acc[4][2];
  for (int i = 0; i < 4; ++i)
    for (int j = 0; j < 2; ++j) acc[i][j] = (f32x4){0.f, 0.f, 0.f, 0.f};
  int rrow = lane >> 2, rseg = lane & 3;
  for (int kc = 0; kc < 256; kc += 32) {
    gl_lds16(pwbf + (size_t)(o0 + w * 16 + rrow) * CC + kc + rseg * 8,
             &A_l[(w * 16) * 32]);
#pragma unroll
    for (int i = 0; i < 2; ++i) {
      int row = i * 64 + w * 16 + rrow;
      gl_lds16(attnT + ((size_t)b * PP + p0 + row) * CC + kc + rseg * 8,
               &B_l[(i * 64 + w * 16) * 32]);
    }
    __syncthreads();
    short8 af[4], bfr[2];
    for (int i = 0; i < 4; ++i)
      af[i] = *(const short8*)&A_l[(i * 16 + ln) * 32 + lq * 8];
    for (int j = 0; j < 2; ++j)
      bfr[j] = *(const short8*)&B_l[(w * 32 + j * 16 + ln) * 32 + lq * 8];
    for (int i = 0; i < 4; ++i)
      for (int j = 0; j < 2; ++j) acc[i][j] = mfma16(af[i], bfr[j], acc[i][j]);
    __syncthreads();
  }
  for (int i = 0; i < 4; ++i) {
    for (int j = 0; j < 2; ++j) {
      int p = p0 + w * 32 + j * 16 + ln;
      for (int r = 0; r < 4; ++r) {
        int o = o0 + i * 16 + lq * 4 + r;
        size_t idx = ((size_t)b * CC + o) * PP + p;
        out[idx] = x[idx] + projb[o] + acc[i][j][r];
      }
    }
  }
}

// ---------------------------------------------------------------------------
extern "C" void kernel_launch(void* const* d_in, const int* in_sizes, int n_in,
                              void* d_out, int out_size, void* d_ws, size_t ws_size,
                              hipStream_t stream) {
  const float* x = (const float*)d_in[0];
  const float* gamma = (const float*)d_in[1];
  const float* beta = (const float*)d_in[2];
  const float* qkvw = (const float*)d_in[3];
  const float* qkvb = (const float*)d_in[4];
  const float* projw = (const float*)d_in[5];
  const float* projb = (const float*)d_in[6];
  float* out = (float*)d_out;
  char* ws = (char*)d_ws;

  float2* part = (float2*)(ws + 0);                        //  4 KB
  unsigned short* xnT = (unsigned short*)(ws + 16384);     //  4 MB
  unsigned short* wall = (unsigned short*)(ws + 4210688);  // 512 KB
  unsigned short* pwbf = wall + 768 * 256;
  unsigned short* qb = (unsigned short*)(ws + 4734976);      // 4 MB
  unsigned short* kb = (unsigned short*)(ws + 8929280);      // 4 MB
  unsigned short* vT = (unsigned short*)(ws + 13123584);     // 4 MB
  unsigned short* attnT = (unsigned short*)(ws + 17317888);  // 4 MB

  prep<<<768, 256, 0, stream>>>(x, part, qkvw, projw, wall);
  norm_t<<<dim3(16, 4, 8), 256, 0, stream>>>(x, part, gamma, beta, xnT);
  qkv_gemm<<<dim3(8, 6, 8), 256, 0, stream>>>(xnT, wall, qkvb, qb, kb, vT);
  attn<<<dim3(16, 4, 8), 256, 0, stream>>>(qb, kb, vT, attnT);
  proj_gemm<<<dim3(8, 4, 8), 256, 0, stream>>>(attnT, pwbf, projb, x, out);
}

// Round 10
// 126.040 us; speedup vs baseline: 1.0763x; 1.0062x over previous
//
#include <hip/hip_runtime.h>
#include <stdint.h>

typedef __attribute__((ext_vector_type(8))) short short8;
typedef __attribute__((ext_vector_type(4))) float f32x4;

#define BB 8
#define CC 256
#define PP 1024
#define NH 4
#define DH 64

__device__ __forceinline__ unsigned short f2bf(float f) {
  union { float f; unsigned u; } v; v.f = f;
  unsigned r = v.u + 0x7FFFu + ((v.u >> 16) & 1u);
  return (unsigned short)(r >> 16);
}

__device__ __forceinline__ float bf2f(unsigned short u) {
  union { unsigned u; float f; } v; v.u = ((unsigned)u) << 16;
  return v.f;
}

__device__ __forceinline__ f32x4 mfma16(short8 a, short8 b, f32x4 c) {
  return __builtin_amdgcn_mfma_f32_16x16x32_bf16(a, b, c, 0, 0, 0);
}

// -------- Kernel 1: GroupNorm partial sums (512 blk) + weight cvt (256 blk) -
__global__ __launch_bounds__(256) void prep(
    const float* __restrict__ x, float2* __restrict__ part,
    const float* __restrict__ qkvw, const float* __restrict__ projw,
    unsigned short* __restrict__ wall) {
  int blk = blockIdx.x;
  int tid = threadIdx.x;
  if (blk < 512) {
    int sl = blk & 7, g = (blk >> 3) & 7, b = blk >> 6;
    const float4* xb =
        (const float4*)(x + (size_t)(b * CC + g * 32) * PP) + sl * 1024;
    float s = 0.f, q = 0.f;
    for (int i = tid; i < 1024; i += 256) {
      float4 v = xb[i];
      s += v.x + v.y + v.z + v.w;
      q += v.x * v.x + v.y * v.y + v.z * v.z + v.w * v.w;
    }
    for (int off = 32; off > 0; off >>= 1) {
      s += __shfl_down(s, off);
      q += __shfl_down(q, off);
    }
    __shared__ float rs[4], rq[4];
    int w = tid >> 6;
    if ((tid & 63) == 0) { rs[w] = s; rq[w] = q; }
    __syncthreads();
    if (tid == 0)
      part[blk] = make_float2(rs[0] + rs[1] + rs[2] + rs[3],
                              rq[0] + rq[1] + rq[2] + rq[3]);
  } else {
    int i4 = (blk - 512) * 256 + tid;  // 65536 float4s total
    float4 v = (i4 < 49152) ? ((const float4*)qkvw)[i4]
                            : ((const float4*)projw)[i4 - 49152];
    ushort4 o;
    o.x = f2bf(v.x); o.y = f2bf(v.y); o.z = f2bf(v.z); o.w = f2bf(v.w);
    ((ushort4*)wall)[i4] = o;
  }
}

// ------------- Kernel 2: finish stats + normalize + transpose --------------
// -> xnT[b][p][c] bf16
__global__ __launch_bounds__(256) void norm_t(
    const float* __restrict__ x, const float2* __restrict__ part,
    const float* __restrict__ gamma, const float* __restrict__ beta,
    unsigned short* __restrict__ xnT) {
  int p0 = blockIdx.x * 64, c0 = blockIdx.y * 64, b = blockIdx.z;
  int tid = threadIdx.x;
  __shared__ float ms[2], rstd[2];
  __shared__ unsigned short T[64][72];
  if (tid < 2) {
    int g = blockIdx.y * 2 + tid;
    float S = 0.f, Q = 0.f;
    for (int i = 0; i < 8; ++i) {
      float2 pp = part[b * 64 + g * 8 + i];
      S += pp.x; Q += pp.y;
    }
    float mean = S * (1.f / 32768.f);
    float var = Q * (1.f / 32768.f) - mean * mean;
    ms[tid] = mean;
    rstd[tid] = rsqrtf(var + 1e-5f);
  }
  __syncthreads();
  for (int it = 0; it < 4; ++it) {
    int l = tid + 256 * it;
    int cc = l >> 4, p4 = l & 15;
    int c = c0 + cc, gi = cc >> 5;
    float sc = rstd[gi] * gamma[c];
    float sh = beta[c] - ms[gi] * sc;
    float4 v = *(const float4*)(x + (size_t)(b * CC + c) * PP + p0 + p4 * 4);
    T[p4 * 4 + 0][cc] = f2bf(v.x * sc + sh);
    T[p4 * 4 + 1][cc] = f2bf(v.y * sc + sh);
    T[p4 * 4 + 2][cc] = f2bf(v.z * sc + sh);
    T[p4 * 4 + 3][cc] = f2bf(v.w * sc + sh);
  }
  __syncthreads();
  for (int it = 0; it < 2; ++it) {
    int l = tid + 256 * it;
    int p = l >> 3, seg = l & 7;
    *(short8*)(xnT + ((size_t)b * PP + p0 + p) * CC + c0 + seg * 8) =
        *(const short8*)&T[p][seg * 8];
  }
}

// ------------- Kernel 3: QKV GEMM (computed [p][o]) ------------------------
// q,k: [b][h][p][64]; v stored TRANSPOSED: vT[b][h][ch][p]
// q pre-scaled by dh^-0.5 * log2(e) so attn can use exp2 directly.
__global__ __launch_bounds__(256) void qkv_gemm(
    const unsigned short* __restrict__ xnT, const unsigned short* __restrict__ wbf,
    const float* __restrict__ qkvb, unsigned short* __restrict__ qb,
    unsigned short* __restrict__ kb, unsigned short* __restrict__ vT) {
  int p0 = blockIdx.x * 128, o0 = blockIdx.y * 128, b = blockIdx.z;
  int tid = threadIdx.x;
  int w = tid >> 6, lane = tid & 63, lq = lane >> 4, ln = lane & 15;
  int wy = w >> 1, wx = w & 1;
  __shared__ unsigned short A_l[128][40];
  __shared__ unsigned short B_l[128][40];
  f32x4 acc[4][4];
  for (int i = 0; i < 4; ++i)
    for (int j = 0; j < 4; ++j) acc[i][j] = (f32x4){0.f, 0.f, 0.f, 0.f};
  for (int kc = 0; kc < 256; kc += 32) {
    for (int it = 0; it < 2; ++it) {
      int l = tid + 256 * it;
      int row = l >> 2, seg = l & 3;
      *(short8*)&A_l[row][seg * 8] =
          *(const short8*)(xnT + ((size_t)b * PP + p0 + row) * CC + kc + seg * 8);
      *(short8*)&B_l[row][seg * 8] =
          *(const short8*)(wbf + (size_t)(o0 + row) * CC + kc + seg * 8);
    }
    __syncthreads();
    short8 af[4], bf[4];
    for (int i = 0; i < 4; ++i)
      af[i] = *(const short8*)&A_l[wy * 64 + i * 16 + ln][lq * 8];
    for (int j = 0; j < 4; ++j)
      bf[j] = *(const short8*)&B_l[wx * 64 + j * 16 + ln][lq * 8];
    for (int i = 0; i < 4; ++i)
      for (int j = 0; j < 4; ++j) acc[i][j] = mfma16(af[i], bf[j], acc[i][j]);
    __syncthreads();
  }
  for (int i = 0; i < 4; ++i) {
    for (int j = 0; j < 4; ++j) {
      int o = o0 + wx * 64 + j * 16 + ln;
      int s = o >> 8, h = (o >> 6) & 3, ch = o & 63;
      float bias = qkvb[o];
      // 0.125 * log2(e): exp(0.125*s) == exp2(0.1803369*s)
      float mul = (s == 0) ? 0.18033688011112042f : 1.0f;
      size_t bh = (size_t)b * NH + h;
      for (int r = 0; r < 4; ++r) {
        int p = p0 + wy * 64 + i * 16 + lq * 4 + r;
        unsigned short val = f2bf((acc[i][j][r] + bias) * mul);
        if (s == 2) {
          vT[(bh * DH + ch) * PP + p] = val;
        } else {
          unsigned short* dst = (s == 0) ? qb : kb;
          dst[(bh * PP + p) * DH + ch] = val;
        }
      }
    }
  }
}

// ------------- Kernel 4: flash attention v3 — small blocks, high occupancy -
// d-tile 32, e-tile 64; 4 waves = (d-half dw) x (e-half ew). Grid 1024 ->
// 4 blocks/CU co-resident (LDS 23 KB), 16 waves/CU: per-iter dependency
// chain (8 MFMA + 8 exp2 + private-P round-trip) hidden by cross-block TLP.
// S^T form: QK mfma(K_frag, Q_frag) -> C col=d, rows=e (verified R6).
// Epilogue: 2-partial bf16 O reduce through aliased LDS (verified R7).
// No-max softmax safe: s_log2 = 0.1803*q.k ~ N(0,1.44); clamp 86.
__global__ __launch_bounds__(256) void attn(
    const unsigned short* __restrict__ qb, const unsigned short* __restrict__ kb,
    const unsigned short* __restrict__ vT, unsigned short* __restrict__ attnT) {
  int d0 = blockIdx.x * 32, h = blockIdx.y, b = blockIdx.z;
  int tid = threadIdx.x;
  int w = tid >> 6, lane = tid & 63, lq = lane >> 4, ln = lane & 15;
  int dw = w & 1, ew = w >> 1;
  size_t bh = (size_t)b * NH + h;
  const unsigned short* qbase = qb + bh * PP * DH;
  const unsigned short* kbase = kb + bh * PP * DH;
  const unsigned short* vbase = vT + bh * DH * PP;

  __shared__ __align__(16) char SM[23552];
  unsigned short (*K_l)[72] = (unsigned short (*)[72])(SM);         // [64e][72]
  unsigned short (*V_l)[72] = (unsigned short (*)[72])(SM + 9216);  // [64ch][72]
  unsigned short* Pw = (unsigned short*)(SM + 18432) + w * 640;     // [16d][40]
  unsigned short (*Obf)[72] = (unsigned short (*)[72])(SM);         // alias K_l
  float* lsums = (float*)(SM + 9216);                               // alias V_l

  int srow = tid >> 2, sseg = tid & 3;  // staging: 64 rows x 4 x 16-short segs

  short8 qf[2];
  {
    int d = d0 + dw * 16 + ln;
    qf[0] = *(const short8*)(qbase + (size_t)d * DH + lq * 8);
    qf[1] = *(const short8*)(qbase + (size_t)d * DH + 32 + lq * 8);
  }
  float lsum = 0.f;  // partial row-sum for col d = dw*16+ln over e-half ew
  f32x4 o_acc[4];
  for (int i = 0; i < 4; ++i) o_acc[i] = (f32x4){0.f, 0.f, 0.f, 0.f};

  short8 kr[2], vr[2];
#pragma unroll
  for (int i = 0; i < 2; ++i) {
    kr[i] = *(const short8*)(kbase + (size_t)srow * DH + sseg * 16 + i * 8);
    vr[i] = *(const short8*)(vbase + (size_t)srow * PP + sseg * 16 + i * 8);
  }

  for (int e0 = 0; e0 < PP; e0 += 64) {
#pragma unroll
    for (int i = 0; i < 2; ++i) {
      *(short8*)&K_l[srow][sseg * 16 + i * 8] = kr[i];
      *(short8*)&V_l[srow][sseg * 16 + i * 8] = vr[i];
    }
    if (e0 + 64 < PP) {
      int en = e0 + 64;
#pragma unroll
      for (int i = 0; i < 2; ++i) {
        kr[i] = *(const short8*)(kbase + (size_t)(en + srow) * DH + sseg * 16 + i * 8);
        vr[i] = *(const short8*)(vbase + (size_t)srow * PP + en + sseg * 16 + i * 8);
      }
    }
    __syncthreads();
    // QK over this wave's (16 d) x (32 e) patch: 2 e-subtiles
    f32x4 sc[2];
#pragma unroll
    for (int es = 0; es < 2; ++es) {
      int er = ew * 32 + es * 16 + ln;
      f32x4 a = (f32x4){0.f, 0.f, 0.f, 0.f};
      a = mfma16(*(const short8*)&K_l[er][lq * 8], qf[0], a);
      a = mfma16(*(const short8*)&K_l[er][32 + lq * 8], qf[1], a);
      sc[es] = a;  // col d = dw*16+ln, row e = ew*32+es*16+lq*4+r
    }
    // exp2 + pack -> private P (b64), accumulate row-sum
#pragma unroll
    for (int es = 0; es < 2; ++es) {
      float p0 = exp2f(fminf(sc[es][0], 86.f));
      float p1 = exp2f(fminf(sc[es][1], 86.f));
      float p2 = exp2f(fminf(sc[es][2], 86.f));
      float p3 = exp2f(fminf(sc[es][3], 86.f));
      lsum += (p0 + p1) + (p2 + p3);
      union { unsigned short u[4]; unsigned long long ll; } pk;
      pk.u[0] = f2bf(p0); pk.u[1] = f2bf(p1);
      pk.u[2] = f2bf(p2); pk.u[3] = f2bf(p3);
      *(unsigned long long*)&Pw[ln * 40 + es * 16 + lq * 4] = pk.ll;
    }
    // PV: partial O[ch][d] += V[ch][e-half] * P[d][e-half] (one K=32 chunk)
    short8 pb = *(const short8*)&Pw[ln * 40 + lq * 8];
#pragma unroll
    for (int cs = 0; cs < 4; ++cs) {
      short8 va = *(const short8*)&V_l[cs * 16 + ln][ew * 32 + lq * 8];
      o_acc[cs] = mfma16(va, pb, o_acc[cs]);
    }
    __syncthreads();
  }
  // partial row-sum: reduce over quads (all lq hold same col d)
  {
    float s = lsum;
    s += __shfl_xor(s, 16);
    s += __shfl_xor(s, 32);
    if (lq == 0) lsums[w * 16 + ln] = s;
  }
  // bf16 partial O -> Obf[w*16+ln][ch]
#pragma unroll
  for (int cs = 0; cs < 4; ++cs) {
    union { unsigned short u[4]; unsigned long long ll; } pk;
#pragma unroll
    for (int r = 0; r < 4; ++r) pk.u[r] = f2bf(o_acc[cs][r]);
    *(unsigned long long*)&Obf[w * 16 + ln][cs * 16 + lq * 4] = pk.ll;
  }
  __syncthreads();
  // final: sum the 2 e-half partials, normalize, store direct to global
  {
    int d = tid >> 3, cseg = tid & 7;
    int dl = d & 15, dh2 = d >> 4;
    float inv =
        1.f / (lsums[dh2 * 16 + dl] + lsums[(2 + dh2) * 16 + dl]);
    float o[8];
#pragma unroll
    for (int j = 0; j < 8; ++j) o[j] = 0.f;
#pragma unroll
    for (int ewp = 0; ewp < 2; ++ewp) {
      short8 vv = *(const short8*)&Obf[(ewp * 2 + dh2) * 16 + dl][cseg * 8];
#pragma unroll
      for (int j = 0; j < 8; ++j) o[j] += bf2f((unsigned short)vv[j]);
    }
    union { unsigned short u[8]; short8 s; } pk;
#pragma unroll
    for (int j = 0; j < 8; ++j) pk.u[j] = f2bf(o[j] * inv);
    *(short8*)(attnT + ((size_t)b * PP + d0 + d) * CC + h * DH + cseg * 8) =
        pk.s;
  }
}

// ------------- Kernel 5: proj GEMM + bias + residual (fp32 out) ------------
__global__ __launch_bounds__(256) void proj_gemm(
    const unsigned short* __restrict__ attnT, const unsigned short* __restrict__ pwbf,
    const float* __restrict__ projb, const float* __restrict__ x,
    float* __restrict__ out) {
  int p0 = blockIdx.x * 128, o0 = blockIdx.y * 64, b = blockIdx.z;
  int tid = threadIdx.x;
  int w = tid >> 6, lane = tid & 63, lq = lane >> 4, ln = lane & 15;
  __shared__ unsigned short A_l[64][40];
  __shared__ unsigned short B_l[128][40];
  f32x4 acc[4][2];
  for (int i = 0; i < 4; ++i)
    for (int j = 0; j < 2; ++j) acc[i][j] = (f32x4){0.f, 0.f, 0.f, 0.f};
  for (int kc = 0; kc < 256; kc += 32) {
    {
      int row = tid >> 2, seg = tid & 3;
      *(short8*)&A_l[row][seg * 8] =
          *(const short8*)(pwbf + (size_t)(o0 + row) * CC + kc + seg * 8);
    }
    for (int it = 0; it < 2; ++it) {
      int l = tid + 256 * it;
      int row = l >> 2, seg = l & 3;
      *(short8*)&B_l[row][seg * 8] =
          *(const short8*)(attnT + ((size_t)b * PP + p0 + row) * CC + kc + seg * 8);
    }
    __syncthreads();
    short8 af[4], bfr[2];
    for (int i = 0; i < 4; ++i)
      af[i] = *(const short8*)&A_l[i * 16 + ln][lq * 8];
    for (int j = 0; j < 2; ++j)
      bfr[j] = *(const short8*)&B_l[w * 32 + j * 16 + ln][lq * 8];
    for (int i = 0; i < 4; ++i)
      for (int j = 0; j < 2; ++j) acc[i][j] = mfma16(af[i], bfr[j], acc[i][j]);
    __syncthreads();
  }
  for (int i = 0; i < 4; ++i) {
    for (int j = 0; j < 2; ++j) {
      int p = p0 + w * 32 + j * 16 + ln;
      for (int r = 0; r < 4; ++r) {
        int o = o0 + i * 16 + lq * 4 + r;
        size_t idx = ((size_t)b * CC + o) * PP + p;
        out[idx] = x[idx] + projb[o] + acc[i][j][r];
      }
    }
  }
}

// ---------------------------------------------------------------------------
extern "C" void kernel_launch(void* const* d_in, const int* in_sizes, int n_in,
                              void* d_out, int out_size, void* d_ws, size_t ws_size,
                              hipStream_t stream) {
  const float* x = (const float*)d_in[0];
  const float* gamma = (const float*)d_in[1];
  const float* beta = (const float*)d_in[2];
  const float* qkvw = (const float*)d_in[3];
  const float* qkvb = (const float*)d_in[4];
  const float* projw = (const float*)d_in[5];
  const float* projb = (const float*)d_in[6];
  float* out = (float*)d_out;
  char* ws = (char*)d_ws;

  float2* part = (float2*)(ws + 0);                        //  4 KB
  unsigned short* xnT = (unsigned short*)(ws + 16384);     //  4 MB
  unsigned short* wall = (unsigned short*)(ws + 4210688);  // 512 KB
  unsigned short* pwbf = wall + 768 * 256;
  unsigned short* qb = (unsigned short*)(ws + 4734976);      // 4 MB
  unsigned short* kb = (unsigned short*)(ws + 8929280);      // 4 MB
  unsigned short* vT = (unsigned short*)(ws + 13123584);     // 4 MB
  unsigned short* attnT = (unsigned short*)(ws + 17317888);  // 4 MB

  prep<<<768, 256, 0, stream>>>(x, part, qkvw, projw, wall);
  norm_t<<<dim3(16, 4, 8), 256, 0, stream>>>(x, part, gamma, beta, xnT);
  qkv_gemm<<<dim3(8, 6, 8), 256, 0, stream>>>(xnT, wall, qkvb, qb, kb, vT);
  attn<<<dim3(32, 4, 8), 256, 0, stream>>>(qb, kb, vT, attnT);
  proj_gemm<<<dim3(8, 4, 8), 256, 0, stream>>>(attnT, pwbf, projb, x, out);
}